// Round 1
// baseline (197.041 us; speedup 1.0000x reference)
//
#include <hip/hip_runtime.h>
#include <hip/hip_bf16.h>
#include <stdint.h>
#include <stddef.h>

#define N_ 4096
#define D_ 64
#define I_ 512
#define O_ 512

#define BM 128
#define BN 128
#define BK 64
#define SPLITS 4
#define DPG (D_ / SPLITS)      /* 16 d-values per block */
#define KSTEPS (I_ / BK)       /* 8 */
#define NSTEP (DPG * KSTEPS)   /* 128 */

typedef float  floatx4 __attribute__((ext_vector_type(4)));
typedef short  shortx8 __attribute__((ext_vector_type(8)));

__device__ __forceinline__ void gload_lds16(const void* g, void* l) {
  __builtin_amdgcn_global_load_lds(
      (const __attribute__((address_space(1))) void*)g,
      (__attribute__((address_space(3))) void*)l, 16, 0, 0);
}

__device__ __forceinline__ unsigned short f2bf(float f) {
  union { float f; unsigned int u; } c; c.f = f;
  unsigned int u = c.u;
  return (unsigned short)((u + 0x7fffu + ((u >> 16) & 1u)) >> 16);  // RNE
}

__device__ __forceinline__ void mfma_bf16(floatx4& c, shortx8 a, shortx8 b) {
  asm("v_mfma_f32_16x16x32_bf16 %0, %1, %2, %0" : "+v"(c) : "v"(a), "v"(b));
}

// ---------- pre-pass: x fp32 -> bf16 ----------
__global__ void k_cvt_x(const float* __restrict__ x, unsigned short* __restrict__ xb) {
  int idx = (blockIdx.x * blockDim.x + threadIdx.x) * 8;
  floatx4 a = *(const floatx4*)(x + idx);
  floatx4 b = *(const floatx4*)(x + idx + 4);
  shortx8 o;
  o[0] = (short)f2bf(a[0]); o[1] = (short)f2bf(a[1]);
  o[2] = (short)f2bf(a[2]); o[3] = (short)f2bf(a[3]);
  o[4] = (short)f2bf(b[0]); o[5] = (short)f2bf(b[1]);
  o[6] = (short)f2bf(b[2]); o[7] = (short)f2bf(b[3]);
  *(shortx8*)(xb + idx) = o;
}

// ---------- pre-pass: W[d][i][o] fp32 -> Wt[d][o][i] bf16 (transpose) ----------
__global__ void k_cvt_w(const float* __restrict__ w, unsigned short* __restrict__ wt) {
  __shared__ unsigned short T[64][72];  // padded to dodge bank conflicts on column read
  int bid = blockIdx.x;
  int d  = bid >> 6;
  int it = (bid >> 3) & 7;
  int ot = bid & 7;
  int i0 = it * 64, o0 = ot * 64;
  int t = threadIdx.x;
  const float* wp = w + ((size_t)d * I_ + i0) * O_ + o0;
  #pragma unroll
  for (int j = 0; j < 16; ++j) {
    int idx = j * 256 + t;
    int r = idx >> 6, c = idx & 63;
    T[r][c] = f2bf(wp[(size_t)r * O_ + c]);
  }
  __syncthreads();
  unsigned short* op = wt + ((size_t)d * O_ + o0) * I_ + i0;
  #pragma unroll
  for (int j = 0; j < 16; ++j) {
    int idx = j * 256 + t;
    int r = idx >> 6, c = idx & 63;
    op[(size_t)r * I_ + c] = T[c][r];
  }
}

// ---------- bias: out[n,o] = sum_d var[n,d] * b1[d,o]  (also zero-inits out) ----------
__global__ void k_bias(const float* __restrict__ var, const float* __restrict__ b1,
                       float* __restrict__ out) {
  __shared__ float vs[16][64];
  int n0 = blockIdx.x * 16;
  int t = threadIdx.x;
  #pragma unroll
  for (int j = 0; j < 4; ++j) {
    int idx = j * 256 + t;
    vs[idx >> 6][idx & 63] = var[(size_t)n0 * D_ + idx];
  }
  __syncthreads();
  float a0[16], a1[16];
  #pragma unroll
  for (int r = 0; r < 16; ++r) { a0[r] = 0.f; a1[r] = 0.f; }
  for (int d = 0; d < D_; ++d) {
    float b0 = b1[(size_t)d * O_ + t];
    float bb = b1[(size_t)d * O_ + 256 + t];
    #pragma unroll
    for (int r = 0; r < 16; ++r) { a0[r] += vs[r][d] * b0; a1[r] += vs[r][d] * bb; }
  }
  #pragma unroll
  for (int r = 0; r < 16; ++r) {
    out[(size_t)(n0 + r) * O_ + t]       = a0[r];
    out[(size_t)(n0 + r) * O_ + 256 + t] = a1[r];
  }
}

// ---------- main: split-d batched GEMM with var-scaled dual accumulator ----------
__global__ __launch_bounds__(256, 2) void k_gemm(
    const unsigned short* __restrict__ xb, const unsigned short* __restrict__ wt,
    const float* __restrict__ var, float* __restrict__ out) {
  __shared__ alignas(16) unsigned short lA[2][BM * BK];
  __shared__ alignas(16) unsigned short lB[2][BN * BK];
  __shared__ alignas(16) float lV[DPG * BM];   // [d][row] transposed var tile

  const int tid = threadIdx.x;
  const int bx  = blockIdx.x;
  const int split = bx & (SPLITS - 1);
  const int tile  = bx >> 2;
  const int ot = tile & 3;
  const int mt = tile >> 2;
  const int brow = mt * BM, bcol = ot * BN, d0 = split * DPG;

  const int lane = tid & 63, wid = tid >> 6;
  const int wr = wid >> 1, wc = wid & 1;
  const int l15 = lane & 15, l4 = lane >> 4;

  // stage var transposed: lV[dd*BM + row] = var[brow+row][d0+dd]
  #pragma unroll
  for (int j = 0; j < (DPG * BM) / 256; ++j) {
    int idx = j * 256 + tid;
    int dd = idx >> 7, row = idx & (BM - 1);
    lV[idx] = var[(size_t)(brow + row) * D_ + d0 + dd];
  }

  const floatx4 vzero = {0.f, 0.f, 0.f, 0.f};
  floatx4 master[4][4];
  #pragma unroll
  for (int m = 0; m < 4; ++m)
    #pragma unroll
    for (int n = 0; n < 4; ++n) master[m][n] = vzero;
  floatx4 accd[4][4];

  // stage step s into buffer buf. Linear LDS dest (gload_lds constraint),
  // inverse-XOR-swizzled global source; reads apply the same XOR (rule 21).
  auto stage = [&](int s, int buf) {
    const int d  = d0 + (s >> 3);
    const int kk = s & 7;
    const char* xsrc = (const char*)xb + ((size_t)brow * I_ + (size_t)kk * BK) * 2;
    const char* wsrc = (const char*)wt + (((size_t)d * O_ + bcol) * I_ + (size_t)kk * BK) * 2;
    char* la = (char*)&lA[buf][0];
    char* lb = (char*)&lB[buf][0];
    #pragma unroll
    for (int c = 0; c < 4; ++c) {
      int chunk = c * 256 + tid;          // 1024 chunks of 16B per tile
      int p = chunk << 4;                 // byte pos in linear [128][128B] tile
      int row = p >> 7;
      int colG = (p & 127) ^ ((row & 7) << 4);
      gload_lds16(xsrc + (size_t)row * (I_ * 2) + colG, la + p);
      gload_lds16(wsrc + (size_t)row * (I_ * 2) + colG, lb + p);
    }
  };

  stage(0, 0);

  int s = 0;
  for (int dl = 0; dl < DPG; ++dl) {
    #pragma unroll
    for (int m = 0; m < 4; ++m)
      #pragma unroll
      for (int n = 0; n < 4; ++n) accd[m][n] = vzero;

    for (int kk = 0; kk < KSTEPS; ++kk, ++s) {
      const int buf = s & 1;
      __syncthreads();                       // buf ready (implicit vmcnt drain)
      if (s + 1 < NSTEP) stage(s + 1, buf ^ 1);  // overlap next stage with compute
      #pragma unroll
      for (int ks = 0; ks < 2; ++ks) {
        shortx8 av[4], bv[4];
        #pragma unroll
        for (int m = 0; m < 4; ++m) {
          int row = wr * 64 + m * 16 + l15;
          int cb = ks * 64 + l4 * 16;
          av[m] = *(const shortx8*)((const char*)&lA[buf][0] + row * 128 +
                                    (cb ^ ((row & 7) << 4)));
        }
        #pragma unroll
        for (int n = 0; n < 4; ++n) {
          int row = wc * 64 + n * 16 + l15;
          int cb = ks * 64 + l4 * 16;
          bv[n] = *(const shortx8*)((const char*)&lB[buf][0] + row * 128 +
                                    (cb ^ ((row & 7) << 4)));
        }
        #pragma unroll
        for (int m = 0; m < 4; ++m)
          #pragma unroll
          for (int n = 0; n < 4; ++n)
            mfma_bf16(accd[m][n], av[m], bv[n]);
      }
    }

    // master += var[row, d] * accd   (C/D layout: col=lane&15, row=(lane>>4)*4+r)
    #pragma unroll
    for (int m = 0; m < 4; ++m) {
      floatx4 vv = *(const floatx4*)&lV[dl * BM + wr * 64 + m * 16 + l4 * 4];
      #pragma unroll
      for (int n = 0; n < 4; ++n)
        #pragma unroll
        for (int r = 0; r < 4; ++r)
          master[m][n][r] += vv[r] * accd[m][n][r];
    }
  }

  // epilogue: atomic add onto bias-initialized out
  #pragma unroll
  for (int m = 0; m < 4; ++m) {
    int row0 = brow + wr * 64 + m * 16 + l4 * 4;
    #pragma unroll
    for (int n = 0; n < 4; ++n) {
      int col = bcol + wc * 64 + n * 16 + l15;
      #pragma unroll
      for (int r = 0; r < 4; ++r)
        atomicAdd(out + (size_t)(row0 + r) * O_ + col, master[m][n][r]);
    }
  }
}

// ---------- fallback (only if ws too small for bf16 staging) ----------
__global__ void k_naive(const float* __restrict__ x, const float* __restrict__ var,
                        const float* __restrict__ w, const float* __restrict__ b1,
                        float* __restrict__ out) {
  int n = blockIdx.x;
  int o = blockIdx.y * 128 + threadIdx.x;
  const float* xp = x + (size_t)n * I_;
  float acc = 0.f;
  for (int d = 0; d < D_; ++d) {
    const float* wp = w + (size_t)d * I_ * O_ + o;
    float y = 0.f;
    for (int i = 0; i < I_; ++i) y += xp[i] * wp[(size_t)i * O_];
    acc += var[(size_t)n * D_ + d] * (y + b1[(size_t)d * O_ + o]);
  }
  out[(size_t)n * O_ + o] = acc;
}

extern "C" void kernel_launch(void* const* d_in, const int* in_sizes, int n_in,
                              void* d_out, int out_size, void* d_ws, size_t ws_size,
                              hipStream_t stream) {
  const float* x   = (const float*)d_in[0];
  const float* var = (const float*)d_in[1];
  const float* W   = (const float*)d_in[2];
  const float* b1  = (const float*)d_in[3];
  float* out = (float*)d_out;

  const size_t wt_bytes = (size_t)D_ * I_ * O_ * 2;  // 32 MB
  const size_t xb_bytes = (size_t)N_ * I_ * 2;       // 4 MB
  if (ws_size >= wt_bytes + xb_bytes) {
    unsigned short* wt = (unsigned short*)d_ws;
    unsigned short* xb = (unsigned short*)((char*)d_ws + wt_bytes);
    k_cvt_x<<<dim3((N_ * I_) / (256 * 8)), dim3(256), 0, stream>>>(x, xb);
    k_cvt_w<<<dim3(D_ * 64), dim3(256), 0, stream>>>(W, wt);
    k_bias<<<dim3(N_ / 16), dim3(256), 0, stream>>>(var, b1, out);
    k_gemm<<<dim3((N_ / BM) * (O_ / BN) * SPLITS), dim3(256), 0, stream>>>(xb, wt, var, out);
  } else {
    k_naive<<<dim3(N_, O_ / 128), dim3(128), 0, stream>>>(x, var, W, b1, out);
  }
}

// Round 2
// 190.000 us; speedup vs baseline: 1.0371x; 1.0371x over previous
//
#include <hip/hip_runtime.h>
#include <hip/hip_bf16.h>
#include <stdint.h>
#include <stddef.h>

#define N_ 4096
#define D_ 64
#define I_ 512
#define O_ 512

#define BM 256
#define BN 128
#define BK 64
#define SPLITS 4
#define DPG 16                 /* d-values per block */
#define PAIRS (DPG / 2)        /* 8 */
#define KSTEPS (I_ / BK)       /* 8 */
#define NSTEP (PAIRS * KSTEPS) /* 64 supersteps; each = 1 x-tile + 2 W-tiles */

typedef float  floatx4 __attribute__((ext_vector_type(4)));
typedef short  shortx8 __attribute__((ext_vector_type(8)));

__device__ __forceinline__ void gload_lds16(const void* g, void* l) {
  __builtin_amdgcn_global_load_lds(
      (const __attribute__((address_space(1))) void*)g,
      (__attribute__((address_space(3))) void*)l, 16, 0, 0);
}

__device__ __forceinline__ unsigned short f2bf(float f) {
  union { float f; unsigned int u; } c; c.f = f;
  unsigned int u = c.u;
  return (unsigned short)((u + 0x7fffu + ((u >> 16) & 1u)) >> 16);  // RNE
}

__device__ __forceinline__ void mfma_bf16(floatx4& c, shortx8 a, shortx8 b) {
  asm("v_mfma_f32_16x16x32_bf16 %0, %1, %2, %0" : "+v"(c) : "v"(a), "v"(b));
}

// ---------- pre-pass: x fp32 -> bf16 ----------
__global__ void k_cvt_x(const float* __restrict__ x, unsigned short* __restrict__ xb) {
  int idx = (blockIdx.x * blockDim.x + threadIdx.x) * 8;
  floatx4 a = *(const floatx4*)(x + idx);
  floatx4 b = *(const floatx4*)(x + idx + 4);
  shortx8 o;
  o[0] = (short)f2bf(a[0]); o[1] = (short)f2bf(a[1]);
  o[2] = (short)f2bf(a[2]); o[3] = (short)f2bf(a[3]);
  o[4] = (short)f2bf(b[0]); o[5] = (short)f2bf(b[1]);
  o[6] = (short)f2bf(b[2]); o[7] = (short)f2bf(b[3]);
  *(shortx8*)(xb + idx) = o;
}

// ---------- pre-pass: W[d][i][o] fp32 -> Wt[d][o][i] bf16 (transpose) ----------
__global__ void k_cvt_w(const float* __restrict__ w, unsigned short* __restrict__ wt) {
  __shared__ unsigned short T[64][72];  // padded: column read dodges bank conflicts
  int bid = blockIdx.x;
  int d  = bid >> 6;
  int it = (bid >> 3) & 7;
  int ot = bid & 7;
  int i0 = it * 64, o0 = ot * 64;
  int t = threadIdx.x;
  const float* wp = w + ((size_t)d * I_ + i0) * O_ + o0;
  #pragma unroll
  for (int j = 0; j < 16; ++j) {
    int idx = j * 256 + t;
    int r = idx >> 6, c = idx & 63;
    T[r][c] = f2bf(wp[(size_t)r * O_ + c]);
  }
  __syncthreads();
  unsigned short* op = wt + ((size_t)d * O_ + o0) * I_ + i0;
  #pragma unroll
  for (int j = 0; j < 16; ++j) {
    int idx = j * 256 + t;
    int r = idx >> 6, c = idx & 63;
    op[(size_t)r * I_ + c] = T[c][r];
  }
}

// ---------- bias: out[n,o] = sum_d var[n,d] * b1[d,o]  (zero-init + bias) ----------
__global__ void k_bias(const float* __restrict__ var, const float* __restrict__ b1,
                       float* __restrict__ out) {
  __shared__ float vs[16][64];
  int n0 = blockIdx.x * 16;
  int t = threadIdx.x;
  #pragma unroll
  for (int j = 0; j < 4; ++j) {
    int idx = j * 256 + t;
    vs[idx >> 6][idx & 63] = var[(size_t)n0 * D_ + idx];
  }
  __syncthreads();
  float a0[16], a1[16];
  #pragma unroll
  for (int r = 0; r < 16; ++r) { a0[r] = 0.f; a1[r] = 0.f; }
  for (int d = 0; d < D_; ++d) {
    float b0 = b1[(size_t)d * O_ + t];
    float bb = b1[(size_t)d * O_ + 256 + t];
    #pragma unroll
    for (int r = 0; r < 16; ++r) { a0[r] += vs[r][d] * b0; a1[r] += vs[r][d] * bb; }
  }
  #pragma unroll
  for (int r = 0; r < 16; ++r) {
    out[(size_t)(n0 + r) * O_ + t]       = a0[r];
    out[(size_t)(n0 + r) * O_ + 256 + t] = a1[r];
  }
}

// ---------- main: d-paired split-d GEMM, counted-vmcnt pipeline ----------
__global__ __launch_bounds__(512, 2) void k_gemm(
    const unsigned short* __restrict__ xb, const unsigned short* __restrict__ wt,
    const float* __restrict__ var, float* __restrict__ out) {
  __shared__ alignas(16) unsigned short lA[2][BM * BK];      // 2 x 32 KB
  __shared__ alignas(16) unsigned short lB[2][2][BN * BK];   // 2 x 2 x 16 KB
  __shared__ alignas(16) float lV[DPG * BM];                 // 16 KB

  const int tid = threadIdx.x;
  const int bid = blockIdx.x;
  // XCD grouping: blocks sharing a W-slice (same ot,split) have bid%8 == g%8
  const int g  = bid & 15;          // (ot, split)
  const int mt = bid >> 4;          // row tile
  const int ot = g >> 2, split = g & 3;
  const int brow = mt * BM, bcol = ot * BN, d0 = split * DPG;

  const int lane = tid & 63, wid = tid >> 6;
  const int wr = wid >> 1, wc = wid & 1;        // 4M x 2N waves, 64x64 each
  const int l15 = lane & 15, l4 = lane >> 4;

  // stage var transposed: lV[dd*BM + row] = var[brow+row][d0+dd]
  #pragma unroll
  for (int j = 0; j < (DPG * BM) / 512; ++j) {
    int idx = j * 512 + tid;
    int dd = idx >> 8, row = idx & (BM - 1);
    lV[idx] = var[(size_t)(brow + row) * D_ + d0 + dd];
  }

  // stage superstep s (pair p = s>>3, kk = s&7): x tile + two W tiles.
  // Linear LDS dest (gload_lds constraint), inverse-XOR-swizzled global src.
  auto stage = [&](int s, int buf) {
    const int p  = s >> 3;
    const int kk = s & 7;
    const int da = d0 + 2 * p;
    const char* xsrc = (const char*)xb + ((size_t)brow * I_ + (size_t)kk * BK) * 2;
    const char* w0 = (const char*)wt + (((size_t)da * O_ + bcol) * I_ + (size_t)kk * BK) * 2;
    const char* w1 = (const char*)wt + (((size_t)(da + 1) * O_ + bcol) * I_ + (size_t)kk * BK) * 2;
    char* la  = (char*)&lA[buf][0];
    char* lb0 = (char*)&lB[buf][0][0];
    char* lb1 = (char*)&lB[buf][1][0];
    #pragma unroll
    for (int c = 0; c < 4; ++c) {               // A: 2048 chunks of 16B
      int pb = (c * 512 + tid) << 4;
      int row = pb >> 7;
      int colG = (pb & 127) ^ ((row & 7) << 4);
      gload_lds16(xsrc + (size_t)row * (I_ * 2) + colG, la + pb);
    }
    #pragma unroll
    for (int c = 0; c < 2; ++c) {               // B0,B1: 1024 chunks each
      int pb = (c * 512 + tid) << 4;
      int row = pb >> 7;
      int colG = (pb & 127) ^ ((row & 7) << 4);
      gload_lds16(w0 + (size_t)row * (I_ * 2) + colG, lb0 + pb);
      gload_lds16(w1 + (size_t)row * (I_ * 2) + colG, lb1 + pb);
    }
  };

  stage(0, 0);

  const floatx4 vzero = {0.f, 0.f, 0.f, 0.f};
  floatx4 master[4][4];
  #pragma unroll
  for (int m = 0; m < 4; ++m)
    #pragma unroll
    for (int n = 0; n < 4; ++n) master[m][n] = vzero;

  __syncthreads();   // lV ready + stage(0) drained (once; counted vmcnt afterwards)

  for (int p = 0; p < PAIRS; ++p) {
    floatx4 acc0[4][4], acc1[4][4];
    #pragma unroll
    for (int m = 0; m < 4; ++m)
      #pragma unroll
      for (int n = 0; n < 4; ++n) { acc0[m][n] = vzero; acc1[m][n] = vzero; }

    for (int kk = 0; kk < KSTEPS; ++kk) {
      const int s = p * KSTEPS + kk;
      const int buf = s & 1;
      if (s + 1 < NSTEP) {
        stage(s + 1, (s + 1) & 1);              // 8 loads in flight across compute
        asm volatile("s_waitcnt vmcnt(8)" ::: "memory");  // wait only for step s
      } else {
        asm volatile("s_waitcnt vmcnt(0)" ::: "memory");
      }
      const char* laB  = (const char*)&lA[buf][0];
      const char* lb0B = (const char*)&lB[buf][0][0];
      const char* lb1B = (const char*)&lB[buf][1][0];
      __builtin_amdgcn_s_setprio(1);
      #pragma unroll
      for (int ks = 0; ks < 2; ++ks) {
        const int cb = ks * 64 + l4 * 16;
        shortx8 av[4];
        #pragma unroll
        for (int m = 0; m < 4; ++m) {
          int row = wr * 64 + m * 16 + l15;
          av[m] = *(const shortx8*)(laB + row * 128 + (cb ^ ((row & 7) << 4)));
        }
        shortx8 bv[4];
        #pragma unroll
        for (int n = 0; n < 4; ++n) {
          int row = wc * 64 + n * 16 + l15;
          bv[n] = *(const shortx8*)(lb0B + row * 128 + (cb ^ ((row & 7) << 4)));
        }
        #pragma unroll
        for (int m = 0; m < 4; ++m)
          #pragma unroll
          for (int n = 0; n < 4; ++n) mfma_bf16(acc0[m][n], av[m], bv[n]);
        #pragma unroll
        for (int n = 0; n < 4; ++n) {
          int row = wc * 64 + n * 16 + l15;
          bv[n] = *(const shortx8*)(lb1B + row * 128 + (cb ^ ((row & 7) << 4)));
        }
        #pragma unroll
        for (int m = 0; m < 4; ++m)
          #pragma unroll
          for (int n = 0; n < 4; ++n) mfma_bf16(acc1[m][n], av[m], bv[n]);
      }
      __builtin_amdgcn_s_setprio(0);
      __builtin_amdgcn_s_barrier();             // buf s free for stage(s+2)
    }

    // master += var[row,da]*acc0 + var[row,da+1]*acc1
    #pragma unroll
    for (int m = 0; m < 4; ++m) {
      int rbase = wr * 64 + m * 16 + l4 * 4;
      floatx4 v0 = *(const floatx4*)&lV[(2 * p) * BM + rbase];
      floatx4 v1 = *(const floatx4*)&lV[(2 * p + 1) * BM + rbase];
      #pragma unroll
      for (int n = 0; n < 4; ++n)
        #pragma unroll
        for (int r = 0; r < 4; ++r)
          master[m][n][r] += v0[r] * acc0[m][n][r] + v1[r] * acc1[m][n][r];
    }
  }

  // epilogue: atomic add onto bias-initialized out
  #pragma unroll
  for (int m = 0; m < 4; ++m) {
    int row0 = brow + wr * 64 + m * 16 + l4 * 4;
    #pragma unroll
    for (int n = 0; n < 4; ++n) {
      int col = bcol + wc * 64 + n * 16 + l15;
      #pragma unroll
      for (int r = 0; r < 4; ++r)
        atomicAdd(out + (size_t)(row0 + r) * O_ + col, master[m][n][r]);
    }
  }
}

// ---------- fallback (only if ws too small for bf16 staging) ----------
__global__ void k_naive(const float* __restrict__ x, const float* __restrict__ var,
                        const float* __restrict__ w, const float* __restrict__ b1,
                        float* __restrict__ out) {
  int n = blockIdx.x;
  int o = blockIdx.y * 128 + threadIdx.x;
  const float* xp = x + (size_t)n * I_;
  float acc = 0.f;
  for (int d = 0; d < D_; ++d) {
    const float* wp = w + (size_t)d * I_ * O_ + o;
    float y = 0.f;
    for (int i = 0; i < I_; ++i) y += xp[i] * wp[(size_t)i * O_];
    acc += var[(size_t)n * D_ + o % 1 * 0 + d] * (y + b1[(size_t)d * O_ + o]);
  }
  out[(size_t)n * O_ + o] = acc;
}

extern "C" void kernel_launch(void* const* d_in, const int* in_sizes, int n_in,
                              void* d_out, int out_size, void* d_ws, size_t ws_size,
                              hipStream_t stream) {
  const float* x   = (const float*)d_in[0];
  const float* var = (const float*)d_in[1];
  const float* W   = (const float*)d_in[2];
  const float* b1  = (const float*)d_in[3];
  float* out = (float*)d_out;

  const size_t wt_bytes = (size_t)D_ * I_ * O_ * 2;  // 32 MB
  const size_t xb_bytes = (size_t)N_ * I_ * 2;       // 4 MB
  if (ws_size >= wt_bytes + xb_bytes) {
    unsigned short* wt = (unsigned short*)d_ws;
    unsigned short* xb = (unsigned short*)((char*)d_ws + wt_bytes);
    k_cvt_x<<<dim3((N_ * I_) / (256 * 8)), dim3(256), 0, stream>>>(x, xb);
    k_cvt_w<<<dim3(D_ * 64), dim3(256), 0, stream>>>(W, wt);
    k_bias<<<dim3(N_ / 16), dim3(256), 0, stream>>>(var, b1, out);
    k_gemm<<<dim3((N_ / BM) * (O_ / BN) * SPLITS), dim3(512), 0, stream>>>(xb, wt, var, out);
  } else {
    k_naive<<<dim3(N_, O_ / 128), dim3(128), 0, stream>>>(x, var, W, b1, out);
  }
}

// Round 5
// 178.535 us; speedup vs baseline: 1.1037x; 1.0642x over previous
//
#include <hip/hip_runtime.h>
#include <hip/hip_bf16.h>
#include <stdint.h>
#include <stddef.h>

#define N_ 4096
#define D_ 64
#define I_ 512
#define O_ 512

#define BM 256
#define BN 128
#define BK 64
#define SPLITS 4
#define DPG 16                 /* d-values per block */
#define PAIRS (DPG / 2)        /* 8 */
#define KSTEPS (I_ / BK)       /* 8 */
#define NSTEP (PAIRS * KSTEPS) /* 64 supersteps */

typedef float  floatx4 __attribute__((ext_vector_type(4)));
typedef short  shortx8 __attribute__((ext_vector_type(8)));

__device__ __forceinline__ void gload_lds16(const void* g, void* l) {
  __builtin_amdgcn_global_load_lds(
      (const __attribute__((address_space(1))) void*)g,
      (__attribute__((address_space(3))) void*)l, 16, 0, 0);
}

__device__ __forceinline__ unsigned short f2bf(float f) {
  union { float f; unsigned int u; } c; c.f = f;
  unsigned int u = c.u;
  return (unsigned short)((u + 0x7fffu + ((u >> 16) & 1u)) >> 16);  // RNE
}

__device__ __forceinline__ void mfma_bf16(floatx4& c, shortx8 a, shortx8 b) {
  asm("v_mfma_f32_16x16x32_bf16 %0, %1, %2, %0" : "+v"(c) : "v"(a), "v"(b));
}

// ---------- pre-pass: x fp32 -> bf16 ----------
__global__ void k_cvt_x(const float* __restrict__ x, unsigned short* __restrict__ xb) {
  int idx = (blockIdx.x * blockDim.x + threadIdx.x) * 8;
  floatx4 a = *(const floatx4*)(x + idx);
  floatx4 b = *(const floatx4*)(x + idx + 4);
  shortx8 o;
  o[0] = (short)f2bf(a[0]); o[1] = (short)f2bf(a[1]);
  o[2] = (short)f2bf(a[2]); o[3] = (short)f2bf(a[3]);
  o[4] = (short)f2bf(b[0]); o[5] = (short)f2bf(b[1]);
  o[6] = (short)f2bf(b[2]); o[7] = (short)f2bf(b[3]);
  *(shortx8*)(xb + idx) = o;
}

// ---------- pre-pass: W[d][i][o] fp32 -> Wt[d][o][i] bf16 (transpose) ----------
__global__ void k_cvt_w(const float* __restrict__ w, unsigned short* __restrict__ wt) {
  __shared__ unsigned short T[64][72];
  int bid = blockIdx.x;
  int d  = bid >> 6;
  int it = (bid >> 3) & 7;
  int ot = bid & 7;
  int i0 = it * 64, o0 = ot * 64;
  int t = threadIdx.x;
  const float* wp = w + ((size_t)d * I_ + i0) * O_ + o0;
  #pragma unroll
  for (int j = 0; j < 16; ++j) {
    int idx = j * 256 + t;
    int r = idx >> 6, c = idx & 63;
    T[r][c] = f2bf(wp[(size_t)r * O_ + c]);
  }
  __syncthreads();
  unsigned short* op = wt + ((size_t)d * O_ + o0) * I_ + i0;
  #pragma unroll
  for (int j = 0; j < 16; ++j) {
    int idx = j * 256 + t;
    int r = idx >> 6, c = idx & 63;
    op[(size_t)r * I_ + c] = T[c][r];
  }
}

// ---------- bias: out[n,o] = sum_d var[n,d] * b1[d,o]  (zero-init + bias) ----------
__global__ void k_bias(const float* __restrict__ var, const float* __restrict__ b1,
                       float* __restrict__ out) {
  __shared__ float vs[16][64];
  int n0 = blockIdx.x * 16;
  int t = threadIdx.x;
  #pragma unroll
  for (int j = 0; j < 4; ++j) {
    int idx = j * 256 + t;
    vs[idx >> 6][idx & 63] = var[(size_t)n0 * D_ + idx];
  }
  __syncthreads();
  float a0[16], a1[16];
  #pragma unroll
  for (int r = 0; r < 16; ++r) { a0[r] = 0.f; a1[r] = 0.f; }
  for (int d = 0; d < D_; ++d) {
    float b0 = b1[(size_t)d * O_ + t];
    float bb = b1[(size_t)d * O_ + 256 + t];
    #pragma unroll
    for (int r = 0; r < 16; ++r) { a0[r] += vs[r][d] * b0; a1[r] += vs[r][d] * bb; }
  }
  #pragma unroll
  for (int r = 0; r < 16; ++r) {
    out[(size_t)(n0 + r) * O_ + t]       = a0[r];
    out[(size_t)(n0 + r) * O_ + 256 + t] = a1[r];
  }
}

// ---------- main: d-paired split-d GEMM, 4-phase interleave ----------
// Staging: R2's known-correct pattern — LINEAR LDS dest (uniform + lane*16,
// the gload_lds HW contract) + inverse-XOR-swizzled GLOBAL source; reads
// apply the same XOR. All 8 staging loads for superstep s+1 are issued in
// ph0/ph1 of s; one vmcnt(0) publication at end of ph3 (loads are 2-3
// phases old by then -> drain ~free).
__global__ __launch_bounds__(512) void k_gemm(
    const unsigned short* __restrict__ xb, const unsigned short* __restrict__ wt,
    const float* __restrict__ var, float* __restrict__ out) {
  __shared__ alignas(16) unsigned short lA[2][BM * BK];      // 2 x 32 KB
  __shared__ alignas(16) unsigned short lB[2][2][BN * BK];   // 2 x 2 x 16 KB
  __shared__ alignas(16) float lV[DPG * BM];                 // 16 KB

  const int tid = threadIdx.x;
  const int bid = blockIdx.x;
  const int g  = bid & 15;          // (ot, split) — XCD-local W-slice sharing
  const int mt = bid >> 4;
  const int ot = g >> 2, split = g & 3;
  const int brow = mt * BM, bcol = ot * BN, d0 = split * DPG;

  const int lane = tid & 63, wid = tid >> 6;
  const int wr = wid >> 1, wc = wid & 1;        // 4M x 2N waves, 64x64 each
  const int l15 = lane & 15, l4 = lane >> 4;

  // stage var transposed: lV[dd*BM + row] = var[brow+row][d0+dd]
  #pragma unroll
  for (int j = 0; j < (DPG * BM) / 512; ++j) {
    int idx = j * 512 + tid;
    int dd = idx >> 8, row = idx & (BM - 1);
    lV[idx] = var[(size_t)(brow + row) * D_ + d0 + dd];
  }

  const char* xbB = (const char*)xb;
  const char* wtB = (const char*)wt;

  // A chunks c in [0,4): 512 threads x 16B each = 8KB; LDS dest linear.
  auto stage_A2 = [&](int s, int buf, int c0) {
    const int kk = s & 7;
    const char* xsrc = xbB + ((size_t)brow * I_ + (size_t)kk * BK) * 2;
    char* la = (char*)&lA[buf][0];
    #pragma unroll
    for (int c = c0; c < c0 + 2; ++c) {
      int pb = (c * 512 + tid) << 4;
      int row = pb >> 7;
      int colG = (pb & 127) ^ ((row & 7) << 4);
      gload_lds16(xsrc + (size_t)row * (I_ * 2) + colG, la + pb);
    }
  };
  // B chunk c in [0,2): one 16B load into each of lB0/lB1.
  auto stage_B2 = [&](int s, int buf, int c) {
    const int p = s >> 3, kk = s & 7;
    const int da = d0 + 2 * p;
    const char* w0 = wtB + (((size_t)da * O_ + bcol) * I_ + (size_t)kk * BK) * 2;
    int pb = (c * 512 + tid) << 4;
    int row = pb >> 7;
    int colG = (pb & 127) ^ ((row & 7) << 4);
    gload_lds16(w0 + (size_t)row * (I_ * 2) + colG, (char*)&lB[buf][0][0] + pb);
    gload_lds16(w0 + (size_t)O_ * I_ * 2 + (size_t)row * (I_ * 2) + colG,
                (char*)&lB[buf][1][0] + pb);
  };

  // prologue: full superstep-0 tile
  stage_A2(0, 0, 0); stage_A2(0, 0, 2); stage_B2(0, 0, 0); stage_B2(0, 0, 1);

  const floatx4 vzero = {0.f, 0.f, 0.f, 0.f};
  floatx4 master[4][4];
  #pragma unroll
  for (int m = 0; m < 4; ++m)
    #pragma unroll
    for (int n = 0; n < 4; ++n) master[m][n] = vzero;

  asm volatile("s_waitcnt vmcnt(0)" ::: "memory");
  __syncthreads();   // stage(0) + lV published

  for (int p = 0; p < PAIRS; ++p) {
    floatx4 acc0[4][4], acc1[4][4];
    #pragma unroll
    for (int m = 0; m < 4; ++m)
      #pragma unroll
      for (int n = 0; n < 4; ++n) { acc0[m][n] = vzero; acc1[m][n] = vzero; }

    for (int kk = 0; kk < KSTEPS; ++kk) {
      const int s = p * KSTEPS + kk;
      const int buf = s & 1;
      const bool pre = (s + 1 < NSTEP);
      const char* laB  = (const char*)&lA[buf][0];
      const char* lb0B = (const char*)&lB[buf][0][0];
      const char* lb1B = (const char*)&lB[buf][1][0];
      shortx8 av[4], bv[4];

      // ---- ph0: read av/bv0(ks0) | issue A(s+1) | MFMA->acc0 ----
      #pragma unroll
      for (int m = 0; m < 4; ++m) {
        int row = wr * 64 + m * 16 + l15;
        av[m] = *(const shortx8*)(laB + row * 128 + ((l4 * 16) ^ ((row & 7) << 4)));
      }
      #pragma unroll
      for (int n = 0; n < 4; ++n) {
        int row = wc * 64 + n * 16 + l15;
        bv[n] = *(const shortx8*)(lb0B + row * 128 + ((l4 * 16) ^ ((row & 7) << 4)));
      }
      if (pre) { stage_A2(s + 1, buf ^ 1, 0); stage_A2(s + 1, buf ^ 1, 2); }
      __builtin_amdgcn_s_barrier();
      asm volatile("s_waitcnt lgkmcnt(0)" ::: "memory");
      __builtin_amdgcn_sched_barrier(0);
      __builtin_amdgcn_s_setprio(1);
      #pragma unroll
      for (int m = 0; m < 4; ++m)
        #pragma unroll
        for (int n = 0; n < 4; ++n) mfma_bf16(acc0[m][n], av[m], bv[n]);
      __builtin_amdgcn_s_setprio(0);
      __builtin_amdgcn_s_barrier();

      // ---- ph1: read bv1(ks0) | issue B(s+1) | MFMA->acc1 ----
      #pragma unroll
      for (int n = 0; n < 4; ++n) {
        int row = wc * 64 + n * 16 + l15;
        bv[n] = *(const shortx8*)(lb1B + row * 128 + ((l4 * 16) ^ ((row & 7) << 4)));
      }
      if (pre) { stage_B2(s + 1, buf ^ 1, 0); stage_B2(s + 1, buf ^ 1, 1); }
      __builtin_amdgcn_s_barrier();
      asm volatile("s_waitcnt lgkmcnt(0)" ::: "memory");
      __builtin_amdgcn_sched_barrier(0);
      __builtin_amdgcn_s_setprio(1);
      #pragma unroll
      for (int m = 0; m < 4; ++m)
        #pragma unroll
        for (int n = 0; n < 4; ++n) mfma_bf16(acc1[m][n], av[m], bv[n]);
      __builtin_amdgcn_s_setprio(0);
      __builtin_amdgcn_s_barrier();

      // ---- ph2: read av/bv0(ks1) | MFMA->acc0 ----
      #pragma unroll
      for (int m = 0; m < 4; ++m) {
        int row = wr * 64 + m * 16 + l15;
        av[m] = *(const shortx8*)(laB + row * 128 + ((64 + l4 * 16) ^ ((row & 7) << 4)));
      }
      #pragma unroll
      for (int n = 0; n < 4; ++n) {
        int row = wc * 64 + n * 16 + l15;
        bv[n] = *(const shortx8*)(lb0B + row * 128 + ((64 + l4 * 16) ^ ((row & 7) << 4)));
      }
      __builtin_amdgcn_s_barrier();
      asm volatile("s_waitcnt lgkmcnt(0)" ::: "memory");
      __builtin_amdgcn_sched_barrier(0);
      __builtin_amdgcn_s_setprio(1);
      #pragma unroll
      for (int m = 0; m < 4; ++m)
        #pragma unroll
        for (int n = 0; n < 4; ++n) mfma_bf16(acc0[m][n], av[m], bv[n]);
      __builtin_amdgcn_s_setprio(0);
      __builtin_amdgcn_s_barrier();

      // ---- ph3: read bv1(ks1) | MFMA->acc1 | publish tile(s+1) ----
      #pragma unroll
      for (int n = 0; n < 4; ++n) {
        int row = wc * 64 + n * 16 + l15;
        bv[n] = *(const shortx8*)(lb1B + row * 128 + ((64 + l4 * 16) ^ ((row & 7) << 4)));
      }
      __builtin_amdgcn_s_barrier();
      asm volatile("s_waitcnt lgkmcnt(0)" ::: "memory");
      __builtin_amdgcn_sched_barrier(0);
      __builtin_amdgcn_s_setprio(1);
      #pragma unroll
      for (int m = 0; m < 4; ++m)
        #pragma unroll
        for (int n = 0; n < 4; ++n) mfma_bf16(acc1[m][n], av[m], bv[n]);
      __builtin_amdgcn_s_setprio(0);
      asm volatile("s_waitcnt vmcnt(0)" ::: "memory");  // publish tile s+1
      __builtin_amdgcn_s_barrier();
    }

    // master += var[row,da]*acc0 + var[row,da+1]*acc1
    #pragma unroll
    for (int m = 0; m < 4; ++m) {
      int rbase = wr * 64 + m * 16 + l4 * 4;
      floatx4 v0 = *(const floatx4*)&lV[(2 * p) * BM + rbase];
      floatx4 v1 = *(const floatx4*)&lV[(2 * p + 1) * BM + rbase];
      #pragma unroll
      for (int n = 0; n < 4; ++n)
        #pragma unroll
        for (int r = 0; r < 4; ++r)
          master[m][n][r] += v0[r] * acc0[m][n][r] + v1[r] * acc1[m][n][r];
    }
  }

  // epilogue: atomic add onto bias-initialized out
  #pragma unroll
  for (int m = 0; m < 4; ++m) {
    int row0 = brow + wr * 64 + m * 16 + l4 * 4;
    #pragma unroll
    for (int n = 0; n < 4; ++n) {
      int col = bcol + wc * 64 + n * 16 + l15;
      #pragma unroll
      for (int r = 0; r < 4; ++r)
        atomicAdd(out + (size_t)(row0 + r) * O_ + col, master[m][n][r]);
    }
  }
}

// ---------- fallback (only if ws too small for bf16 staging) ----------
__global__ void k_naive(const float* __restrict__ x, const float* __restrict__ var,
                        const float* __restrict__ w, const float* __restrict__ b1,
                        float* __restrict__ out) {
  int n = blockIdx.x;
  int o = blockIdx.y * 128 + threadIdx.x;
  const float* xp = x + (size_t)n * I_;
  float acc = 0.f;
  for (int d = 0; d < D_; ++d) {
    const float* wp = w + (size_t)d * I_ * O_ + o;
    float y = 0.f;
    for (int i = 0; i < I_; ++i) y += xp[i] * wp[(size_t)i * O_];
    acc += var[(size_t)n * D_ + d] * (y + b1[(size_t)d * O_ + o]);
  }
  out[(size_t)n * O_ + o] = acc;
}

extern "C" void kernel_launch(void* const* d_in, const int* in_sizes, int n_in,
                              void* d_out, int out_size, void* d_ws, size_t ws_size,
                              hipStream_t stream) {
  const float* x   = (const float*)d_in[0];
  const float* var = (const float*)d_in[1];
  const float* W   = (const float*)d_in[2];
  const float* b1  = (const float*)d_in[3];
  float* out = (float*)d_out;

  const size_t wt_bytes = (size_t)D_ * I_ * O_ * 2;  // 32 MB
  const size_t xb_bytes = (size_t)N_ * I_ * 2;       // 4 MB
  if (ws_size >= wt_bytes + xb_bytes) {
    unsigned short* wt = (unsigned short*)d_ws;
    unsigned short* xb = (unsigned short*)((char*)d_ws + wt_bytes);
    k_cvt_x<<<dim3((N_ * I_) / (256 * 8)), dim3(256), 0, stream>>>(x, xb);
    k_cvt_w<<<dim3(D_ * 64), dim3(256), 0, stream>>>(W, wt);
    k_bias<<<dim3(N_ / 16), dim3(256), 0, stream>>>(var, b1, out);
    k_gemm<<<dim3((N_ / BM) * (O_ / BN) * SPLITS), dim3(512), 0, stream>>>(xb, wt, var, out);
  } else {
    k_naive<<<dim3(N_, O_ / 128), dim3(128), 0, stream>>>(x, var, W, b1, out);
  }
}